// Round 2
// baseline (285.142 us; speedup 1.0000x reference)
//
#include <hip/hip_runtime.h>
#include <hip/hip_bf16.h>

#define BB 4
#define SS 1024
#define DDIM 1024
#define HH 16
#define MROWS (BB * SS)

typedef __attribute__((ext_vector_type(8))) short bf16x8;
typedef __attribute__((ext_vector_type(4))) float f32x4;

static __device__ __forceinline__ short f2bf(float x) {
    union { __hip_bfloat16 h; short s; } u;
    u.h = __float2bfloat16(x);
    return u.s;
}

// C[M,N] = A[M,K] @ W[K,N]. A is f32 or bf16 (A_F32), W is f32 (converted to
// bf16 while staging), C written as f32 or bf16 (C_F32). fp32 MFMA accumulate.
// 128x128 tile, BK=32, 256 threads (4 waves, 2x2), each wave 64x64 via 4x4 MFMA 16x16x32.
template<bool A_F32, bool C_F32>
__global__ __launch_bounds__(256) void gemm128(const void* __restrict__ Av,
                                               const float* __restrict__ W,
                                               void* __restrict__ Cv,
                                               int M, int N, int K) {
    __shared__ short sA[128][32];   // [m][k]
    __shared__ short sW[128][32];   // [n][k]  (W transposed on staging)
    const int tid = threadIdx.x;
    const int lane = tid & 63, wid = tid >> 6;
    const int wr = wid >> 1, wc = wid & 1;
    const int g = lane >> 4, l15 = lane & 15;
    const int by = blockIdx.y, bx = blockIdx.x;

    f32x4 acc[4][4] = {};

    for (int k0 = 0; k0 < K; k0 += 32) {
        __syncthreads();
        // stage A: 512 chunks of 8 elements, 2 per thread
        {
            int c = tid;
#pragma unroll
            for (int it = 0; it < 2; ++it, c += 256) {
                int row = c >> 2, co = (c & 3) << 3;
                if constexpr (A_F32) {
                    const float* A = (const float*)Av;
                    const float* p = A + (size_t)(by * 128 + row) * K + k0 + co;
                    float4 x0 = *(const float4*)p;
                    float4 x1 = *(const float4*)(p + 4);
                    short* d = &sA[row][co];
                    d[0] = f2bf(x0.x); d[1] = f2bf(x0.y);
                    d[2] = f2bf(x0.z); d[3] = f2bf(x0.w);
                    d[4] = f2bf(x1.x); d[5] = f2bf(x1.y);
                    d[6] = f2bf(x1.z); d[7] = f2bf(x1.w);
                } else {
                    const short* A = (const short*)Av;
                    *(bf16x8*)(&sA[row][co]) =
                        *(const bf16x8*)(A + (size_t)(by * 128 + row) * K + k0 + co);
                }
            }
        }
        // stage W transposed: read f32 rows of W (contiguous n), convert, scatter to sW[n][k]
        {
            int c = tid;
#pragma unroll
            for (int it = 0; it < 2; ++it, c += 256) {
                int kl = c >> 4, no = (c & 15) << 3;
                const float* p = W + (size_t)(k0 + kl) * N + bx * 128 + no;
                float4 w0 = *(const float4*)p;
                float4 w1 = *(const float4*)(p + 4);
                sW[no + 0][kl] = f2bf(w0.x); sW[no + 1][kl] = f2bf(w0.y);
                sW[no + 2][kl] = f2bf(w0.z); sW[no + 3][kl] = f2bf(w0.w);
                sW[no + 4][kl] = f2bf(w1.x); sW[no + 5][kl] = f2bf(w1.y);
                sW[no + 6][kl] = f2bf(w1.z); sW[no + 7][kl] = f2bf(w1.w);
            }
        }
        __syncthreads();

        bf16x8 af[4], bfr[4];
#pragma unroll
        for (int i = 0; i < 4; ++i)
            af[i] = *(const bf16x8*)(&sA[wr * 64 + i * 16 + l15][g * 8]);
#pragma unroll
        for (int j = 0; j < 4; ++j)
            bfr[j] = *(const bf16x8*)(&sW[wc * 64 + j * 16 + l15][g * 8]);
#pragma unroll
        for (int i = 0; i < 4; ++i)
#pragma unroll
            for (int j = 0; j < 4; ++j)
                acc[i][j] = __builtin_amdgcn_mfma_f32_16x16x32_bf16(af[i], bfr[j], acc[i][j], 0, 0, 0);
    }

#pragma unroll
    for (int i = 0; i < 4; ++i)
#pragma unroll
        for (int j = 0; j < 4; ++j)
#pragma unroll
            for (int r = 0; r < 4; ++r) {
                int row = by * 128 + wr * 64 + i * 16 + g * 4 + r;
                int col = bx * 128 + wc * 64 + j * 16 + l15;
                if constexpr (C_F32)
                    ((float*)Cv)[(size_t)row * N + col] = acc[i][j][r];
                else
                    ((short*)Cv)[(size_t)row * N + col] = f2bf(acc[i][j][r]);
            }
}

// Flash-style attention per (b, h, 64-query-row tile). bf16 in (workspace), bf16 out.
// Block: 256 threads = 4 waves, each wave owns 16 query rows.
// Key tiles of 32; QK^T and PV via 16x16x32 MFMA; online softmax.
// q/k/v in [B,S,D] layout with d = h*64 + e. Output head-interleaved: d = e*H + h.
__global__ __launch_bounds__(256) void attn(const short* __restrict__ q,
                                            const short* __restrict__ k,
                                            const short* __restrict__ v,
                                            const int* __restrict__ vlens,
                                            short* __restrict__ att) {
    const int qt = blockIdx.x;   // 0..15 (query tile of 64)
    const int h  = blockIdx.y;   // 0..15
    const int b  = blockIdx.z;   // 0..3
    const int tid = threadIdx.x;
    const int lane = tid & 63, wid = tid >> 6;
    const int g = lane >> 4, l15 = lane & 15;
    const int vlen = vlens[b];

    __shared__ short sK[32][64];       // [key][d]
    __shared__ short sVT[64][32];      // [e][key]
    __shared__ short sP[4][16][32];    // per-wave P scratch [s][key]

    const int srow = qt * 64 + wid * 16 + l15;
    const short* qrow = q + ((size_t)(b * SS + srow)) * DDIM + h * 64;
    bf16x8 qf[2];
    qf[0] = *(const bf16x8*)(qrow + g * 8);
    qf[1] = *(const bf16x8*)(qrow + 32 + g * 8);

    float m_run[4], l_run[4];
#pragma unroll
    for (int r = 0; r < 4; ++r) { m_run[r] = -1e30f; l_run[r] = 0.0f; }
    f32x4 oacc[4] = {};

    const int ntiles = (vlen + 31) >> 5;
    for (int t = 0; t < ntiles; ++t) {
        const int kb = t * 32;
        __syncthreads();
        // stage K tile [32][64] and V^T tile [64][32]; one 16B chunk per thread
        {
            int key = tid >> 3, d0 = (tid & 7) << 3;
            size_t base = ((size_t)(b * SS + kb + key)) * DDIM + h * 64 + d0;
            *(bf16x8*)(&sK[key][d0]) = *(const bf16x8*)(k + base);
            bf16x8 vv = *(const bf16x8*)(v + base);
#pragma unroll
            for (int j = 0; j < 8; ++j) sVT[d0 + j][key] = vv[j];
        }
        __syncthreads();

        // scores: 2 key-subtiles of 16
        f32x4 sacc[2] = {};
#pragma unroll
        for (int kg = 0; kg < 2; ++kg) {
            bf16x8 kf0 = *(const bf16x8*)(&sK[kg * 16 + l15][g * 8]);
            bf16x8 kf1 = *(const bf16x8*)(&sK[kg * 16 + l15][32 + g * 8]);
            sacc[kg] = __builtin_amdgcn_mfma_f32_16x16x32_bf16(qf[0], kf0, sacc[kg], 0, 0, 0);
            sacc[kg] = __builtin_amdgcn_mfma_f32_16x16x32_bf16(qf[1], kf1, sacc[kg], 0, 0, 0);
        }

        // online softmax per query row (row = g*4 + r; cols = 16 lanes of the group)
        float f[4];
#pragma unroll
        for (int r = 0; r < 4; ++r) {
            float s0 = sacc[0][r] * 0.125f;
            float s1 = sacc[1][r] * 0.125f;
            if (kb + l15 >= vlen)      s0 = -1e30f;
            if (kb + 16 + l15 >= vlen) s1 = -1e30f;
            float tmax = fmaxf(s0, s1);
#pragma unroll
            for (int off = 1; off < 16; off <<= 1)
                tmax = fmaxf(tmax, __shfl_xor(tmax, off));
            float mn = fmaxf(m_run[r], tmax);
            f[r] = __expf(m_run[r] - mn);
            m_run[r] = mn;
            float p0 = __expf(s0 - mn);
            float p1 = __expf(s1 - mn);
            float rs = p0 + p1;
#pragma unroll
            for (int off = 1; off < 16; off <<= 1)
                rs += __shfl_xor(rs, off);
            l_run[r] = l_run[r] * f[r] + rs;
            sP[wid][g * 4 + r][l15]      = f2bf(p0);
            sP[wid][g * 4 + r][16 + l15] = f2bf(p1);
        }
        __syncthreads();

        // PV: rescale O then accumulate P @ V
        bf16x8 pf = *(const bf16x8*)(&sP[wid][l15][g * 8]);
#pragma unroll
        for (int n = 0; n < 4; ++n) {
#pragma unroll
            for (int r = 0; r < 4; ++r) oacc[n][r] *= f[r];
            bf16x8 vf = *(const bf16x8*)(&sVT[n * 16 + l15][g * 8]);
            oacc[n] = __builtin_amdgcn_mfma_f32_16x16x32_bf16(pf, vf, oacc[n], 0, 0, 0);
        }
    }

    // write O / l, head-interleaved: att[b][s][e*H + h]
#pragma unroll
    for (int n = 0; n < 4; ++n)
#pragma unroll
        for (int r = 0; r < 4; ++r) {
            float o = oacc[n][r] / l_run[r];
            int sg = qt * 64 + wid * 16 + g * 4 + r;
            int e = n * 16 + l15;
            att[((size_t)(b * SS + sg)) * DDIM + e * HH + h] = f2bf(o);
        }
}

extern "C" void kernel_launch(void* const* d_in, const int* in_sizes, int n_in,
                              void* d_out, int out_size, void* d_ws, size_t ws_size,
                              hipStream_t stream) {
    const float* queries = (const float*)d_in[0];
    const float* keys    = (const float*)d_in[1];
    const float* values  = (const float*)d_in[2];
    const int*   vlens   = (const int*)d_in[3];
    const float* Wq      = (const float*)d_in[4];
    const float* Wk      = (const float*)d_in[5];
    const float* Wv      = (const float*)d_in[6];
    const float* Wo      = (const float*)d_in[7];
    float* out = (float*)d_out;

    short* ws = (short*)d_ws;
    const size_t sz = (size_t)MROWS * DDIM;  // 4M elements
    short* q_ws   = ws;
    short* k_ws   = ws + sz;
    short* v_ws   = ws + 2 * sz;
    short* att_ws = ws + 3 * sz;

    dim3 ggrid(DDIM / 128, MROWS / 128);
    gemm128<true, false><<<ggrid, 256, 0, stream>>>(queries, Wq, q_ws, MROWS, DDIM, DDIM);
    gemm128<true, false><<<ggrid, 256, 0, stream>>>(keys,    Wk, k_ws, MROWS, DDIM, DDIM);
    gemm128<true, false><<<ggrid, 256, 0, stream>>>(values,  Wv, v_ws, MROWS, DDIM, DDIM);

    dim3 agrid(SS / 64, HH, BB);
    attn<<<agrid, 256, 0, stream>>>(q_ws, k_ws, v_ws, vlens, att_ws);

    gemm128<false, true><<<ggrid, 256, 0, stream>>>(att_ws, Wo, out, MROWS, DDIM, DDIM);
}

// Round 4
// 176.004 us; speedup vs baseline: 1.6201x; 1.6201x over previous
//
#include <hip/hip_runtime.h>
#include <hip/hip_bf16.h>

#define BB 4
#define SS 1024
#define DDIM 1024
#define HH 16
#define MROWS (BB * SS)

typedef __attribute__((ext_vector_type(8))) short bf16x8;
typedef __attribute__((ext_vector_type(4))) float f32x4;

static __device__ __forceinline__ short f2bf(float x) {
    union { __hip_bfloat16 h; short s; } u;
    u.h = __float2bfloat16(x);
    return u.s;
}

#define GL_LDS16(gp, lp)                                                      \
    __builtin_amdgcn_global_load_lds(                                         \
        (const __attribute__((address_space(1))) void*)(gp),                  \
        (__attribute__((address_space(3))) void*)(lp), 16, 0, 0)

// W [K,N] f32  ->  Wt [N,K] bf16.  64x64 tiles, 256 threads.
__global__ __launch_bounds__(256) void transposeW(const float* __restrict__ W,
                                                  short* __restrict__ Wt) {
    __shared__ short sT[64][72];   // +8 pad breaks column-read conflicts
    const int t = threadIdx.x;
    const int k0 = blockIdx.y * 64, n0 = blockIdx.x * 64;
    {
        int r = t >> 2, cq = (t & 3) << 4;   // 16 f32 per thread along the row
        const float* p = W + (size_t)(k0 + r) * DDIM + n0 + cq;
        float4 a = ((const float4*)p)[0], b = ((const float4*)p)[1];
        float4 c = ((const float4*)p)[2], d = ((const float4*)p)[3];
        short* dst = &sT[r][cq];
        dst[0]  = f2bf(a.x); dst[1]  = f2bf(a.y); dst[2]  = f2bf(a.z); dst[3]  = f2bf(a.w);
        dst[4]  = f2bf(b.x); dst[5]  = f2bf(b.y); dst[6]  = f2bf(b.z); dst[7]  = f2bf(b.w);
        dst[8]  = f2bf(c.x); dst[9]  = f2bf(c.y); dst[10] = f2bf(c.z); dst[11] = f2bf(c.w);
        dst[12] = f2bf(d.x); dst[13] = f2bf(d.y); dst[14] = f2bf(d.z); dst[15] = f2bf(d.w);
    }
    __syncthreads();
    {
        int n = t >> 2, kq = (t & 3) << 4;
        bf16x8 o0, o1;
#pragma unroll
        for (int j = 0; j < 8; ++j) o0[j] = sT[kq + j][n];
#pragma unroll
        for (int j = 0; j < 8; ++j) o1[j] = sT[kq + 8 + j][n];
        short* q = Wt + (size_t)(n0 + n) * DDIM + k0 + kq;
        *(bf16x8*)q = o0;
        *(bf16x8*)(q + 8) = o1;
    }
}

// C[M,N] = A[M,K] @ Bt[N,K]^T.  A f32 (in-flight cvt) or bf16 (global_load_lds);
// Bt bf16 via global_load_lds; C f32 or bf16.  fp32 MFMA accumulate.
// BM=128 BN=64 BK=32, 256 threads (4 waves 2x2), wave tile 64x32 (4x2 frags).
template<bool A_F32, bool C_F32>
__global__ __launch_bounds__(256) void gemm(const void* __restrict__ Av,
                                            const short* __restrict__ Bt,
                                            void* __restrict__ Cv,
                                            int M, int N, int K) {
    __shared__ short sA[128][32];   // 8 KB
    __shared__ short sB[64][32];    // 4 KB
    const int tid = threadIdx.x;
    const int lane = tid & 63, wid = tid >> 6;
    const int wr = wid >> 1, wc = wid & 1;
    const int g = lane >> 4, l15 = lane & 15;
    const int by = blockIdx.y, bx = blockIdx.x;

    f32x4 acc[4][2] = {};

    for (int k0 = 0; k0 < K; k0 += 32) {
        __syncthreads();
        // ---- stage A tile 128x32 (4 chunks of 16B per 64B row) ----
        if constexpr (A_F32) {
            const float* A = (const float*)Av;
            int c = tid;
#pragma unroll
            for (int it = 0; it < 2; ++it, c += 256) {
                int row = c >> 2, co = (c & 3) << 3;
                const float* p = A + (size_t)(by * 128 + row) * K + k0 + co;
                float4 x0 = ((const float4*)p)[0];
                float4 x1 = ((const float4*)p)[1];
                bf16x8 vv;
                vv[0] = f2bf(x0.x); vv[1] = f2bf(x0.y); vv[2] = f2bf(x0.z); vv[3] = f2bf(x0.w);
                vv[4] = f2bf(x1.x); vv[5] = f2bf(x1.y); vv[6] = f2bf(x1.z); vv[7] = f2bf(x1.w);
                *(bf16x8*)(&sA[row][co]) = vv;
            }
        } else {
            const short* A = (const short*)Av;
#pragma unroll
            for (int it = 0; it < 2; ++it) {
                int c = it * 256 + tid;
                int row = c >> 2, off = (c & 3) << 3;   // FIXED: 4 chunks/row
                GL_LDS16(A + (size_t)(by * 128 + row) * K + k0 + off,
                         (char*)&sA[0][0] + c * 16);
            }
        }
        // ---- stage B tile 64x32 (bf16, pre-transposed) ----
        {
            int row = tid >> 2, off = (tid & 3) << 3;
            GL_LDS16(Bt + (size_t)(bx * 64 + row) * K + k0 + off,
                     (char*)&sB[0][0] + tid * 16);
        }
        __syncthreads();

        bf16x8 af[4], bfr[2];
#pragma unroll
        for (int i = 0; i < 4; ++i)
            af[i] = *(const bf16x8*)(&sA[wr * 64 + i * 16 + l15][g * 8]);
#pragma unroll
        for (int j = 0; j < 2; ++j)
            bfr[j] = *(const bf16x8*)(&sB[wc * 32 + j * 16 + l15][g * 8]);
#pragma unroll
        for (int i = 0; i < 4; ++i)
#pragma unroll
            for (int j = 0; j < 2; ++j)
                acc[i][j] = __builtin_amdgcn_mfma_f32_16x16x32_bf16(af[i], bfr[j], acc[i][j], 0, 0, 0);
    }

#pragma unroll
    for (int i = 0; i < 4; ++i)
#pragma unroll
        for (int j = 0; j < 2; ++j)
#pragma unroll
            for (int r = 0; r < 4; ++r) {
                int row = by * 128 + wr * 64 + i * 16 + g * 4 + r;
                int col = bx * 64 + wc * 32 + j * 16 + l15;
                if constexpr (C_F32)
                    ((float*)Cv)[(size_t)row * N + col] = acc[i][j][r];
                else
                    ((short*)Cv)[(size_t)row * N + col] = f2bf(acc[i][j][r]);
            }
}

// Flash-style attention per (b, h, 64-query-row tile). bf16 in/out (workspace).
__global__ __launch_bounds__(256) void attn(const short* __restrict__ q,
                                            const short* __restrict__ k,
                                            const short* __restrict__ v,
                                            const int* __restrict__ vlens,
                                            short* __restrict__ att) {
    const int qt = blockIdx.x;
    const int h  = blockIdx.y;
    const int b  = blockIdx.z;
    const int tid = threadIdx.x;
    const int lane = tid & 63, wid = tid >> 6;
    const int g = lane >> 4, l15 = lane & 15;
    const int vlen = vlens[b];

    __shared__ short sK[32][64];
    __shared__ short sVT[64][32];
    __shared__ short sP[4][16][32];

    const int srow = qt * 64 + wid * 16 + l15;
    const short* qrow = q + ((size_t)(b * SS + srow)) * DDIM + h * 64;
    bf16x8 qf[2];
    qf[0] = *(const bf16x8*)(qrow + g * 8);
    qf[1] = *(const bf16x8*)(qrow + 32 + g * 8);

    float m_run[4], l_run[4];
#pragma unroll
    for (int r = 0; r < 4; ++r) { m_run[r] = -1e30f; l_run[r] = 0.0f; }
    f32x4 oacc[4] = {};

    const int ntiles = (vlen + 31) >> 5;
    for (int t = 0; t < ntiles; ++t) {
        const int kb = t * 32;
        __syncthreads();
        {
            int key = tid >> 3, d0 = (tid & 7) << 3;
            size_t base = ((size_t)(b * SS + kb + key)) * DDIM + h * 64 + d0;
            *(bf16x8*)(&sK[key][d0]) = *(const bf16x8*)(k + base);
            bf16x8 vv = *(const bf16x8*)(v + base);
#pragma unroll
            for (int j = 0; j < 8; ++j) sVT[d0 + j][key] = vv[j];
        }
        __syncthreads();

        f32x4 sacc[2] = {};
#pragma unroll
        for (int kg = 0; kg < 2; ++kg) {
            bf16x8 kf0 = *(const bf16x8*)(&sK[kg * 16 + l15][g * 8]);
            bf16x8 kf1 = *(const bf16x8*)(&sK[kg * 16 + l15][32 + g * 8]);
            sacc[kg] = __builtin_amdgcn_mfma_f32_16x16x32_bf16(qf[0], kf0, sacc[kg], 0, 0, 0);
            sacc[kg] = __builtin_amdgcn_mfma_f32_16x16x32_bf16(qf[1], kf1, sacc[kg], 0, 0, 0);
        }

        float f[4];
#pragma unroll
        for (int r = 0; r < 4; ++r) {
            float s0 = sacc[0][r] * 0.125f;
            float s1 = sacc[1][r] * 0.125f;
            if (kb + l15 >= vlen)      s0 = -1e30f;
            if (kb + 16 + l15 >= vlen) s1 = -1e30f;
            float tmax = fmaxf(s0, s1);
#pragma unroll
            for (int off = 1; off < 16; off <<= 1)
                tmax = fmaxf(tmax, __shfl_xor(tmax, off));
            float mn = fmaxf(m_run[r], tmax);
            f[r] = __expf(m_run[r] - mn);
            m_run[r] = mn;
            float p0 = __expf(s0 - mn);
            float p1 = __expf(s1 - mn);
            float rs = p0 + p1;
#pragma unroll
            for (int off = 1; off < 16; off <<= 1)
                rs += __shfl_xor(rs, off);
            l_run[r] = l_run[r] * f[r] + rs;
            sP[wid][g * 4 + r][l15]      = f2bf(p0);
            sP[wid][g * 4 + r][16 + l15] = f2bf(p1);
        }
        __syncthreads();

        bf16x8 pf = *(const bf16x8*)(&sP[wid][l15][g * 8]);
#pragma unroll
        for (int n = 0; n < 4; ++n) {
#pragma unroll
            for (int r = 0; r < 4; ++r) oacc[n][r] *= f[r];
            bf16x8 vf = *(const bf16x8*)(&sVT[n * 16 + l15][g * 8]);
            oacc[n] = __builtin_amdgcn_mfma_f32_16x16x32_bf16(pf, vf, oacc[n], 0, 0, 0);
        }
    }

#pragma unroll
    for (int n = 0; n < 4; ++n)
#pragma unroll
        for (int r = 0; r < 4; ++r) {
            float o = oacc[n][r] / l_run[r];
            int sg = qt * 64 + wid * 16 + g * 4 + r;
            int e = n * 16 + l15;
            att[((size_t)(b * SS + sg)) * DDIM + e * HH + h] = f2bf(o);
        }
}

extern "C" void kernel_launch(void* const* d_in, const int* in_sizes, int n_in,
                              void* d_out, int out_size, void* d_ws, size_t ws_size,
                              hipStream_t stream) {
    const float* queries = (const float*)d_in[0];
    const float* keys    = (const float*)d_in[1];
    const float* values  = (const float*)d_in[2];
    const int*   vlens   = (const int*)d_in[3];
    const float* Wq      = (const float*)d_in[4];
    const float* Wk      = (const float*)d_in[5];
    const float* Wv      = (const float*)d_in[6];
    const float* Wo      = (const float*)d_in[7];
    float* out = (float*)d_out;

    short* ws = (short*)d_ws;
    const size_t sz = (size_t)MROWS * DDIM;  // 4M elems per buffer
    short* q_ws   = ws;            // 8 MB
    short* k_ws   = ws + sz;       // 8 MB
    short* v_ws   = ws + 2 * sz;   // 8 MB
    short* att_ws = ws + 3 * sz;   // 8 MB
    // Wt (2 MB) time-shares dead regions on the serial stream:
    short* wt_a = att_ws;  // dead until attn runs
    short* wt_o = q_ws;    // dead after attn consumes q

    dim3 tgrid(16, 16);
    dim3 ggrid(DDIM / 64, MROWS / 128);
    dim3 agrid(SS / 64, HH, BB);

    transposeW<<<tgrid, 256, 0, stream>>>(Wq, wt_a);
    gemm<true, false><<<ggrid, 256, 0, stream>>>(queries, wt_a, q_ws, MROWS, DDIM, DDIM);
    transposeW<<<tgrid, 256, 0, stream>>>(Wk, wt_a);
    gemm<true, false><<<ggrid, 256, 0, stream>>>(keys, wt_a, k_ws, MROWS, DDIM, DDIM);
    transposeW<<<tgrid, 256, 0, stream>>>(Wv, wt_a);
    gemm<true, false><<<ggrid, 256, 0, stream>>>(values, wt_a, v_ws, MROWS, DDIM, DDIM);

    attn<<<agrid, 256, 0, stream>>>(q_ws, k_ws, v_ws, vlens, att_ws);

    transposeW<<<tgrid, 256, 0, stream>>>(Wo, wt_o);
    gemm<false, true><<<ggrid, 256, 0, stream>>>(att_ws, wt_o, out, MROWS, DDIM, DDIM);
}

// Round 5
// 156.319 us; speedup vs baseline: 1.8241x; 1.1259x over previous
//
#include <hip/hip_runtime.h>
#include <hip/hip_bf16.h>

#define BB 4
#define SS 1024
#define DDIM 1024
#define HH 16
#define MROWS (BB * SS)

typedef __attribute__((ext_vector_type(8))) short bf16x8;
typedef __attribute__((ext_vector_type(4))) float f32x4;

static __device__ __forceinline__ short f2bf(float x) {
    union { __hip_bfloat16 h; short s; } u;
    u.h = __float2bfloat16(x);
    return u.s;
}

#define GL_LDS16(gp, lp)                                                      \
    __builtin_amdgcn_global_load_lds(                                         \
        (const __attribute__((address_space(1))) void*)(gp),                  \
        (__attribute__((address_space(3))) void*)(lp), 16, 0, 0)

// ---------------------------------------------------------------------------
// Weight transpose+convert: W [K,N] f32 -> Wt [N,K] bf16. 64x64 tiles.
// z selects one of up to 3 weight matrices (Wt stride 1M elements).
__global__ __launch_bounds__(256) void transposeW3(const float* __restrict__ W0,
                                                   const float* __restrict__ W1,
                                                   const float* __restrict__ W2,
                                                   short* __restrict__ Wt) {
    const int z = blockIdx.z;
    const float* W = (z == 0) ? W0 : (z == 1) ? W1 : W2;
    short* dst = Wt + (size_t)z * DDIM * DDIM;
    __shared__ short sT[64][72];
    const int t = threadIdx.x;
    const int k0 = blockIdx.y * 64, n0 = blockIdx.x * 64;
    {
        int r = t >> 2, cq = (t & 3) << 4;
        const float* p = W + (size_t)(k0 + r) * DDIM + n0 + cq;
        float4 a = ((const float4*)p)[0], b = ((const float4*)p)[1];
        float4 c = ((const float4*)p)[2], d = ((const float4*)p)[3];
        short* dp = &sT[r][cq];
        dp[0]  = f2bf(a.x); dp[1]  = f2bf(a.y); dp[2]  = f2bf(a.z); dp[3]  = f2bf(a.w);
        dp[4]  = f2bf(b.x); dp[5]  = f2bf(b.y); dp[6]  = f2bf(b.z); dp[7]  = f2bf(b.w);
        dp[8]  = f2bf(c.x); dp[9]  = f2bf(c.y); dp[10] = f2bf(c.z); dp[11] = f2bf(c.w);
        dp[12] = f2bf(d.x); dp[13] = f2bf(d.y); dp[14] = f2bf(d.z); dp[15] = f2bf(d.w);
    }
    __syncthreads();
    {
        int n = t >> 2, kq = (t & 3) << 4;
        bf16x8 o0, o1;
#pragma unroll
        for (int j = 0; j < 8; ++j) o0[j] = sT[kq + j][n];
#pragma unroll
        for (int j = 0; j < 8; ++j) o1[j] = sT[kq + 8 + j][n];
        short* q = dst + (size_t)(n0 + n) * DDIM + k0 + kq;
        *(bf16x8*)q = o0;
        *(bf16x8*)(q + 8) = o1;
    }
}

// ---------------------------------------------------------------------------
// C[M,N] = A[M,K] @ Bt[N,K]^T.  BM=128 BN=64 BK=64, double-buffered LDS,
// XOR-swizzled tiles (slot' = slot ^ (row&7), 16B slots), XCD-chunked grid.
// A: f32 (reg-staged cvt) or bf16 (global_load_lds w/ pre-swizzled source).
template<bool A_F32, bool C_F32>
__global__ __launch_bounds__(256) void gemm(const void* __restrict__ Av,
                                            const short* __restrict__ Bt,
                                            void* __restrict__ Cv,
                                            int M, int N, int K, int NBX) {
    // sA[buf]: 128 rows x 64 shorts (128B row); sB[buf]: 64 rows x 64 shorts
    __shared__ short sA[2][128 * 64];
    __shared__ short sB[2][64 * 64];

    const int tid = threadIdx.x;
    const int lane = tid & 63, wid = tid >> 6;
    const int wr = wid >> 1, wc = wid & 1;
    const int g = lane >> 4, l15 = lane & 15;

    // XCD-chunked swizzle: same-by blocks cluster on one XCD
    const int b   = blockIdx.x;
    const int nb8 = gridDim.x >> 3;          // blocks per XCD
    const int xcd = b & 7, ii = b >> 3;
    const int by  = xcd * (nb8 / NBX) + ii / NBX;
    const int bx  = ii % NBX;

    f32x4 acc[4][2] = {};
    const int nkt = K >> 6;

    // ---- staging helpers (inlined by macros to keep indices literal) ----
    const float* Af  = (const float*)Av;
    const short* Ab  = (const short*)Av;

    // prologue: stage tile 0 into buf 0
    {
        if constexpr (A_F32) {
#pragma unroll
            for (int j = 0; j < 4; ++j) {
                int c = tid + j * 256;
                int row = c >> 3, s = c & 7;           // logical slot s
                const float* p = Af + (size_t)(by * 128 + row) * K + s * 8;
                float4 x0 = ((const float4*)p)[0];
                float4 x1 = ((const float4*)p)[1];
                bf16x8 vv;
                vv[0] = f2bf(x0.x); vv[1] = f2bf(x0.y); vv[2] = f2bf(x0.z); vv[3] = f2bf(x0.w);
                vv[4] = f2bf(x1.x); vv[5] = f2bf(x1.y); vv[6] = f2bf(x1.z); vv[7] = f2bf(x1.w);
                *(bf16x8*)(&sA[0][row * 64 + ((s ^ (row & 7)) << 3)]) = vv;
            }
        } else {
#pragma unroll
            for (int j = 0; j < 4; ++j) {
                int c = tid + j * 256;
                int row = c >> 3, sp = c & 7;          // sp = physical slot
                GL_LDS16(Ab + (size_t)(by * 128 + row) * K + ((sp ^ (row & 7)) << 3),
                         (char*)&sA[0][0] + c * 16);
            }
        }
#pragma unroll
        for (int j = 0; j < 2; ++j) {
            int c = tid + j * 256;
            int row = c >> 3, sp = c & 7;
            GL_LDS16(Bt + (size_t)(bx * 64 + row) * K + ((sp ^ (row & 7)) << 3),
                     (char*)&sB[0][0] + c * 16);
        }
    }

    for (int t = 0; t < nkt; ++t) {
        const int cur = t & 1, nxt = cur ^ 1;
        __syncthreads();   // compiler emits vmcnt(0) lgkmcnt(0): buf[cur] ready

        const bool pre = (t + 1 < nkt);
        float4 ra[4][2];
        if (pre) {
            const int kt = (t + 1) << 6;
            if constexpr (A_F32) {
#pragma unroll
                for (int j = 0; j < 4; ++j) {
                    int c = tid + j * 256;
                    int row = c >> 3, s = c & 7;
                    const float* p = Af + (size_t)(by * 128 + row) * K + kt + s * 8;
                    ra[j][0] = ((const float4*)p)[0];
                    ra[j][1] = ((const float4*)p)[1];
                }
            } else {
#pragma unroll
                for (int j = 0; j < 4; ++j) {
                    int c = tid + j * 256;
                    int row = c >> 3, sp = c & 7;
                    GL_LDS16(Ab + (size_t)(by * 128 + row) * K + kt + ((sp ^ (row & 7)) << 3),
                             (char*)&sA[nxt][0] + c * 16);
                }
            }
#pragma unroll
            for (int j = 0; j < 2; ++j) {
                int c = tid + j * 256;
                int row = c >> 3, sp = c & 7;
                GL_LDS16(Bt + (size_t)(bx * 64 + row) * K + kt + ((sp ^ (row & 7)) << 3),
                         (char*)&sB[nxt][0] + c * 16);
            }
        }

        // fragments (swizzled reads) + MFMA
        bf16x8 af[4][2], bfr[2][2];
#pragma unroll
        for (int i = 0; i < 4; ++i) {
            int row = wr * 64 + i * 16 + l15;
#pragma unroll
            for (int kh = 0; kh < 2; ++kh) {
                int s = kh * 4 + g;
                af[i][kh] = *(const bf16x8*)(&sA[cur][row * 64 + ((s ^ (row & 7)) << 3)]);
            }
        }
#pragma unroll
        for (int j = 0; j < 2; ++j) {
            int row = wc * 32 + j * 16 + l15;
#pragma unroll
            for (int kh = 0; kh < 2; ++kh) {
                int s = kh * 4 + g;
                bfr[j][kh] = *(const bf16x8*)(&sB[cur][row * 64 + ((s ^ (row & 7)) << 3)]);
            }
        }
#pragma unroll
        for (int kh = 0; kh < 2; ++kh)
#pragma unroll
            for (int i = 0; i < 4; ++i)
#pragma unroll
                for (int j = 0; j < 2; ++j)
                    acc[i][j] = __builtin_amdgcn_mfma_f32_16x16x32_bf16(af[i][kh], bfr[j][kh], acc[i][j], 0, 0, 0);

        if (pre) {
            if constexpr (A_F32) {
#pragma unroll
                for (int j = 0; j < 4; ++j) {
                    int c = tid + j * 256;
                    int row = c >> 3, s = c & 7;
                    bf16x8 vv;
                    vv[0] = f2bf(ra[j][0].x); vv[1] = f2bf(ra[j][0].y);
                    vv[2] = f2bf(ra[j][0].z); vv[3] = f2bf(ra[j][0].w);
                    vv[4] = f2bf(ra[j][1].x); vv[5] = f2bf(ra[j][1].y);
                    vv[6] = f2bf(ra[j][1].z); vv[7] = f2bf(ra[j][1].w);
                    *(bf16x8*)(&sA[nxt][row * 64 + ((s ^ (row & 7)) << 3)]) = vv;
                }
            }
        }
    }

#pragma unroll
    for (int i = 0; i < 4; ++i)
#pragma unroll
        for (int j = 0; j < 2; ++j)
#pragma unroll
            for (int r = 0; r < 4; ++r) {
                int row = by * 128 + wr * 64 + i * 16 + g * 4 + r;
                int col = bx * 64 + wc * 32 + j * 16 + l15;
                if constexpr (C_F32)
                    ((float*)Cv)[(size_t)row * N + col] = acc[i][j][r];
                else
                    ((short*)Cv)[(size_t)row * N + col] = f2bf(acc[i][j][r]);
            }
}

// ---------------------------------------------------------------------------
// Flash attention per (b, h, 64-q-rows). 4 waves x 16 q-rows, KV tiles of 32.
// Swizzled sK/sVT/sP; 2 barriers per tile; XCD-clustered (b,h) groups.
__global__ __launch_bounds__(256) void attn(const short* __restrict__ q,
                                            const short* __restrict__ k,
                                            const short* __restrict__ v,
                                            const int* __restrict__ vlens,
                                            short* __restrict__ att) {
    // grid: 1024 blocks flat. Cluster same-(b,h) qt-blocks per XCD.
    const int blk = blockIdx.x;
    const int xcd = blk & 7, ii = blk >> 3;       // ii in [0,128)
    const int hb  = xcd * 8 + (ii >> 4);          // [0,64)
    const int qt  = ii & 15;
    const int bb  = hb >> 4, h = hb & 15;

    const int tid = threadIdx.x;
    const int lane = tid & 63, wid = tid >> 6;
    const int g = lane >> 4, l15 = lane & 15;
    const int vlen = vlens[bb];

    __shared__ short sK[32 * 64];      // [key][d], 16B slots swizzled by key&7
    __shared__ short sV[64 * 32];      // [e][key], cols swizzled by (e>>3)&3
    __shared__ short sP[4][16 * 32];   // per-wave [q][key], cols swz by q>>2

    const int srow = qt * 64 + wid * 16 + l15;
    const short* qrow = q + ((size_t)(bb * SS + srow)) * DDIM + h * 64;
    bf16x8 qf[2];
    qf[0] = *(const bf16x8*)(qrow + g * 8);
    qf[1] = *(const bf16x8*)(qrow + 32 + g * 8);

    float m_run[4], l_run[4];
#pragma unroll
    for (int r = 0; r < 4; ++r) { m_run[r] = -1e30f; l_run[r] = 0.0f; }
    f32x4 oacc[4] = {};

    const int ntiles = (vlen + 31) >> 5;
    for (int t = 0; t < ntiles; ++t) {
        const int kb = t * 32;
        __syncthreads();   // prev tile's PV reads done
        {
            const int key = tid >> 3, d0 = (tid & 7) << 3;
            size_t base = ((size_t)(bb * SS + kb + key)) * DDIM + h * 64 + d0;
            bf16x8 kk = *(const bf16x8*)(k + base);
            bf16x8 vv = *(const bf16x8*)(v + base);
            // sK: slot (d0>>3) -> swizzled by key&7
            *(bf16x8*)(&sK[key * 64 + (((d0 >> 3) ^ (key & 7)) << 3)]) = kk;
            // sV: element (e=d0+j, key), col' = key ^ (((d0>>3)&3)<<3)
            const int colp = key ^ (((d0 >> 3) & 3) << 3);
#pragma unroll
            for (int j = 0; j < 8; ++j) sV[(d0 + j) * 32 + colp] = vv[j];
        }
        __syncthreads();

        // QK^T
        f32x4 sacc[2] = {};
#pragma unroll
        for (int kg = 0; kg < 2; ++kg) {
            int row = kg * 16 + l15;
#pragma unroll
            for (int kh = 0; kh < 2; ++kh) {
                int s = kh * 4 + g;
                bf16x8 kf = *(const bf16x8*)(&sK[row * 64 + ((s ^ (row & 7)) << 3)]);
                sacc[kg] = __builtin_amdgcn_mfma_f32_16x16x32_bf16(qf[kh], kf, sacc[kg], 0, 0, 0);
            }
        }

        // online softmax (rows g*4+r, cols = 16 lanes)
        float f[4];
#pragma unroll
        for (int r = 0; r < 4; ++r) {
            float s0 = sacc[0][r] * 0.125f;
            float s1 = sacc[1][r] * 0.125f;
            if (kb + l15 >= vlen)      s0 = -1e30f;
            if (kb + 16 + l15 >= vlen) s1 = -1e30f;
            float tmax = fmaxf(s0, s1);
#pragma unroll
            for (int off = 1; off < 16; off <<= 1)
                tmax = fmaxf(tmax, __shfl_xor(tmax, off));
            float mn = fmaxf(m_run[r], tmax);
            f[r] = __expf(m_run[r] - mn);
            m_run[r] = mn;
            float p0 = __expf(s0 - mn);
            float p1 = __expf(s1 - mn);
            float rs = p0 + p1;
#pragma unroll
            for (int off = 1; off < 16; off <<= 1)
                rs += __shfl_xor(rs, off);
            l_run[r] = l_run[r] * f[r] + rs;
            const int srw = g * 4 + r;       // (srw>>2)&3 == g
            sP[wid][srw * 32 + (l15 ^ (g << 3))]        = f2bf(p0);
            sP[wid][srw * 32 + ((16 + l15) ^ (g << 3))] = f2bf(p1);
        }
        // no barrier: sP is wave-private; sV/sK protected by next-iter barrier

        // PV
        bf16x8 pf = *(const bf16x8*)(&sP[wid][l15 * 32 + ((g ^ ((l15 >> 2) & 3)) << 3)]);
#pragma unroll
        for (int n = 0; n < 4; ++n) {
#pragma unroll
            for (int r = 0; r < 4; ++r) oacc[n][r] *= f[r];
            const int e = n * 16 + l15;
            bf16x8 vf = *(const bf16x8*)(&sV[e * 32 + ((g ^ ((e >> 3) & 3)) << 3)]);
            oacc[n] = __builtin_amdgcn_mfma_f32_16x16x32_bf16(pf, vf, oacc[n], 0, 0, 0);
        }
    }

    // write head-interleaved: att[bb][s][e*H + h]
#pragma unroll
    for (int n = 0; n < 4; ++n)
#pragma unroll
        for (int r = 0; r < 4; ++r) {
            float o = oacc[n][r] / l_run[r];
            int sg = qt * 64 + wid * 16 + g * 4 + r;
            int e = n * 16 + l15;
            att[((size_t)(bb * SS + sg)) * DDIM + e * HH + h] = f2bf(o);
        }
}

extern "C" void kernel_launch(void* const* d_in, const int* in_sizes, int n_in,
                              void* d_out, int out_size, void* d_ws, size_t ws_size,
                              hipStream_t stream) {
    const float* queries = (const float*)d_in[0];
    const float* keys    = (const float*)d_in[1];
    const float* values  = (const float*)d_in[2];
    const int*   vlens   = (const int*)d_in[3];
    const float* Wq      = (const float*)d_in[4];
    const float* Wk      = (const float*)d_in[5];
    const float* Wv      = (const float*)d_in[6];
    const float* Wo      = (const float*)d_in[7];
    float* out = (float*)d_out;

    short* ws = (short*)d_ws;
    const size_t sz = (size_t)MROWS * DDIM;   // 4M elems
    short* q_ws   = ws;
    short* k_ws   = ws + sz;
    short* v_ws   = ws + 2 * sz;
    short* att_ws = ws + 3 * sz;
    short* wt3  = att_ws;                     // 3M elems, dead until attn
    short* wt_o = q_ws;                       // dead after attn

    const size_t wsz = (size_t)DDIM * DDIM;   // 1M elems per weight

    dim3 tgrid3(16, 16, 3);
    dim3 tgrid1(16, 16, 1);
    const int NBX = DDIM / 64;                // 16
    dim3 ggrid((DDIM / 64) * (MROWS / 128));  // 512 blocks flat
    dim3 agrid((SS / 64) * HH * BB);          // 1024 blocks flat

    transposeW3<<<tgrid3, 256, 0, stream>>>(Wq, Wk, Wv, wt3);
    gemm<true, false><<<ggrid, 256, 0, stream>>>(queries, wt3,           q_ws, MROWS, DDIM, DDIM, NBX);
    gemm<true, false><<<ggrid, 256, 0, stream>>>(keys,    wt3 + wsz,     k_ws, MROWS, DDIM, DDIM, NBX);
    gemm<true, false><<<ggrid, 256, 0, stream>>>(values,  wt3 + 2 * wsz, v_ws, MROWS, DDIM, DDIM, NBX);

    attn<<<agrid, 256, 0, stream>>>(q_ws, k_ws, v_ws, vlens, att_ws);

    transposeW3<<<tgrid1, 256, 0, stream>>>(Wo, Wo, Wo, wt_o);
    gemm<false, true><<<ggrid, 256, 0, stream>>>(att_ws, wt_o, out, MROWS, DDIM, DDIM, NBX);
}

// Round 6
// 147.818 us; speedup vs baseline: 1.9290x; 1.0575x over previous
//
#include <hip/hip_runtime.h>
#include <hip/hip_bf16.h>

#define BB 4
#define SS 1024
#define DDIM 1024
#define HH 16
#define MROWS (BB * SS)

typedef __attribute__((ext_vector_type(8))) short bf16x8;
typedef __attribute__((ext_vector_type(4))) float f32x4;

static __device__ __forceinline__ short f2bf(float x) {
    union { __hip_bfloat16 h; short s; } u;
    u.h = __float2bfloat16(x);
    return u.s;
}

#define GL_LDS16(gp, lp)                                                      \
    __builtin_amdgcn_global_load_lds(                                         \
        (const __attribute__((address_space(1))) void*)(gp),                  \
        (__attribute__((address_space(3))) void*)(lp), 16, 0, 0)

// ---------------------------------------------------------------------------
// Weight transpose+convert: W [K,N] f32 -> Wt [N,K] bf16. 64x64 tiles.
__global__ __launch_bounds__(256) void transposeW3(const float* __restrict__ W0,
                                                   const float* __restrict__ W1,
                                                   const float* __restrict__ W2,
                                                   short* __restrict__ Wt) {
    const int z = blockIdx.z;
    const float* W = (z == 0) ? W0 : (z == 1) ? W1 : W2;
    short* dst = Wt + (size_t)z * DDIM * DDIM;
    __shared__ short sT[64][72];
    const int t = threadIdx.x;
    const int k0 = blockIdx.y * 64, n0 = blockIdx.x * 64;
    {
        int r = t >> 2, cq = (t & 3) << 4;
        const float* p = W + (size_t)(k0 + r) * DDIM + n0 + cq;
        float4 a = ((const float4*)p)[0], b = ((const float4*)p)[1];
        float4 c = ((const float4*)p)[2], d = ((const float4*)p)[3];
        short* dp = &sT[r][cq];
        dp[0]  = f2bf(a.x); dp[1]  = f2bf(a.y); dp[2]  = f2bf(a.z); dp[3]  = f2bf(a.w);
        dp[4]  = f2bf(b.x); dp[5]  = f2bf(b.y); dp[6]  = f2bf(b.z); dp[7]  = f2bf(b.w);
        dp[8]  = f2bf(c.x); dp[9]  = f2bf(c.y); dp[10] = f2bf(c.z); dp[11] = f2bf(c.w);
        dp[12] = f2bf(d.x); dp[13] = f2bf(d.y); dp[14] = f2bf(d.z); dp[15] = f2bf(d.w);
    }
    __syncthreads();
    {
        int n = t >> 2, kq = (t & 3) << 4;
        bf16x8 o0, o1;
#pragma unroll
        for (int j = 0; j < 8; ++j) o0[j] = sT[kq + j][n];
#pragma unroll
        for (int j = 0; j < 8; ++j) o1[j] = sT[kq + 8 + j][n];
        short* q = dst + (size_t)(n0 + n) * DDIM + k0 + kq;
        *(bf16x8*)q = o0;
        *(bf16x8*)(q + 8) = o1;
    }
}

// ---------------------------------------------------------------------------
// C[z][M,N] = A[z][M,K] @ Bt[z][N,K]^T for up to 3 fused problems (z = blk>>8).
// BM=BN=128 BK=64, dbuf LDS, XOR swizzle (slot' = slot ^ (row&7), 16B slots),
// XCD-chunked grid (uniform work). 256 thr = 4 waves (2x2), wave 64x64.
template<bool A_F32, bool C_F32>
__global__ __launch_bounds__(256) void gemm(const void* __restrict__ A0v,
                                            const void* __restrict__ A1v,
                                            const void* __restrict__ A2v,
                                            const short* __restrict__ BtBase,
                                            void* __restrict__ C0v,
                                            void* __restrict__ C1v,
                                            void* __restrict__ C2v) {
    __shared__ short sA[2][128 * 64];   // 16 KB each buf
    __shared__ short sB[2][128 * 64];

    const int tid = threadIdx.x;
    const int lane = tid & 63, wid = tid >> 6;
    const int wr = wid >> 1, wc = wid & 1;
    const int g = lane >> 4, l15 = lane & 15;

    const int blk = blockIdx.x;
    const int z = blk >> 8;                  // problem index
    const int inner = blk & 255;
    const int xcd = inner & 7, ii = inner >> 3;
    const int by = xcd * 4 + (ii >> 3);      // 32 row panels, 4 per XCD
    const int bx = ii & 7;                   // 8 col panels

    const void* Av = (z == 0) ? A0v : (z == 1) ? A1v : A2v;
    const short* Bt = BtBase + (size_t)z * DDIM * DDIM;
    void* Cv = (z == 0) ? C0v : (z == 1) ? C1v : C2v;
    const float* Af = (const float*)Av;
    const short* Ab = (const short*)Av;
    const int K = DDIM;

    f32x4 acc[4][4] = {};
    const int nkt = K >> 6;   // 16

    // ---- prologue: stage tile 0 into buf 0 ----
    if constexpr (A_F32) {
#pragma unroll
        for (int j = 0; j < 4; ++j) {
            int c = tid + j * 256;
            int row = c >> 3, s = c & 7;
            const float* p = Af + (size_t)(by * 128 + row) * K + s * 8;
            float4 x0 = ((const float4*)p)[0];
            float4 x1 = ((const float4*)p)[1];
            bf16x8 vv;
            vv[0] = f2bf(x0.x); vv[1] = f2bf(x0.y); vv[2] = f2bf(x0.z); vv[3] = f2bf(x0.w);
            vv[4] = f2bf(x1.x); vv[5] = f2bf(x1.y); vv[6] = f2bf(x1.z); vv[7] = f2bf(x1.w);
            *(bf16x8*)(&sA[0][row * 64 + ((s ^ (row & 7)) << 3)]) = vv;
        }
    } else {
#pragma unroll
        for (int j = 0; j < 4; ++j) {
            int c = tid + j * 256;
            int row = c >> 3, sp = c & 7;
            GL_LDS16(Ab + (size_t)(by * 128 + row) * K + ((sp ^ (row & 7)) << 3),
                     (char*)&sA[0][0] + c * 16);
        }
    }
#pragma unroll
    for (int j = 0; j < 4; ++j) {
        int c = tid + j * 256;
        int row = c >> 3, sp = c & 7;
        GL_LDS16(Bt + (size_t)(bx * 128 + row) * K + ((sp ^ (row & 7)) << 3),
                 (char*)&sB[0][0] + c * 16);
    }

    for (int t = 0; t < nkt; ++t) {
        const int cur = t & 1, nxt = cur ^ 1;
        __syncthreads();   // buf[cur] ready; prev reads of buf[nxt] done

        const bool pre = (t + 1 < nkt);
        float4 ra[4][2];
        if (pre) {
            const int kt = (t + 1) << 6;
            if constexpr (A_F32) {
#pragma unroll
                for (int j = 0; j < 4; ++j) {
                    int c = tid + j * 256;
                    int row = c >> 3, s = c & 7;
                    const float* p = Af + (size_t)(by * 128 + row) * K + kt + s * 8;
                    ra[j][0] = ((const float4*)p)[0];
                    ra[j][1] = ((const float4*)p)[1];
                }
            } else {
#pragma unroll
                for (int j = 0; j < 4; ++j) {
                    int c = tid + j * 256;
                    int row = c >> 3, sp = c & 7;
                    GL_LDS16(Ab + (size_t)(by * 128 + row) * K + kt + ((sp ^ (row & 7)) << 3),
                             (char*)&sA[nxt][0] + c * 16);
                }
            }
#pragma unroll
            for (int j = 0; j < 4; ++j) {
                int c = tid + j * 256;
                int row = c >> 3, sp = c & 7;
                GL_LDS16(Bt + (size_t)(bx * 128 + row) * K + kt + ((sp ^ (row & 7)) << 3),
                         (char*)&sB[nxt][0] + c * 16);
            }
        }

        bf16x8 af[4][2], bfr[4][2];
#pragma unroll
        for (int i = 0; i < 4; ++i) {
            int row = wr * 64 + i * 16 + l15;
#pragma unroll
            for (int kh = 0; kh < 2; ++kh) {
                int s = kh * 4 + g;
                af[i][kh] = *(const bf16x8*)(&sA[cur][row * 64 + ((s ^ (row & 7)) << 3)]);
            }
        }
#pragma unroll
        for (int j = 0; j < 4; ++j) {
            int row = wc * 64 + j * 16 + l15;
#pragma unroll
            for (int kh = 0; kh < 2; ++kh) {
                int s = kh * 4 + g;
                bfr[j][kh] = *(const bf16x8*)(&sB[cur][row * 64 + ((s ^ (row & 7)) << 3)]);
            }
        }
#pragma unroll
        for (int kh = 0; kh < 2; ++kh)
#pragma unroll
            for (int i = 0; i < 4; ++i)
#pragma unroll
                for (int j = 0; j < 4; ++j)
                    acc[i][j] = __builtin_amdgcn_mfma_f32_16x16x32_bf16(af[i][kh], bfr[j][kh], acc[i][j], 0, 0, 0);

        if (pre) {
            if constexpr (A_F32) {
#pragma unroll
                for (int j = 0; j < 4; ++j) {
                    int c = tid + j * 256;
                    int row = c >> 3, s = c & 7;
                    bf16x8 vv;
                    vv[0] = f2bf(ra[j][0].x); vv[1] = f2bf(ra[j][0].y);
                    vv[2] = f2bf(ra[j][0].z); vv[3] = f2bf(ra[j][0].w);
                    vv[4] = f2bf(ra[j][1].x); vv[5] = f2bf(ra[j][1].y);
                    vv[6] = f2bf(ra[j][1].z); vv[7] = f2bf(ra[j][1].w);
                    *(bf16x8*)(&sA[nxt][row * 64 + ((s ^ (row & 7)) << 3)]) = vv;
                }
            }
        }
    }

#pragma unroll
    for (int i = 0; i < 4; ++i)
#pragma unroll
        for (int j = 0; j < 4; ++j)
#pragma unroll
            for (int r = 0; r < 4; ++r) {
                int row = by * 128 + wr * 64 + i * 16 + g * 4 + r;
                int col = bx * 128 + wc * 64 + j * 16 + l15;
                if constexpr (C_F32)
                    ((float*)Cv)[(size_t)row * DDIM + col] = acc[i][j][r];
                else
                    ((short*)Cv)[(size_t)row * DDIM + col] = f2bf(acc[i][j][r]);
            }
}

// ---------------------------------------------------------------------------
// Flash attention per (b, h, 64-q-rows). 4 waves x 16 q-rows, KV tiles of 64.
// Batch-interleaved block order (load balance); swizzled sK/sV/sP; K staged
// via global_load_lds (pre-swizzled source); 2 barriers per 64-key tile.
__global__ __launch_bounds__(256) void attn(const short* __restrict__ q,
                                            const short* __restrict__ k,
                                            const short* __restrict__ v,
                                            const int* __restrict__ vlens,
                                            short* __restrict__ att) {
    const int blk = blockIdx.x;            // 1024
    const int qt = blk >> 6;               // 0..15
    const int hb = blk & 63;
    const int bb = hb & 3;                 // batch varies fastest
    const int h  = hb >> 2;

    const int tid = threadIdx.x;
    const int lane = tid & 63, wid = tid >> 6;
    const int g = lane >> 4, l15 = lane & 15;
    const int vlen = vlens[bb];

    __shared__ short sK[64 * 64];          // [key][d-slots], swz by key&7
    __shared__ short sV[64 * 64];          // [e][key-slots], swz by e&7
    __shared__ short sP[4][16 * 64];       // per-wave [q][key-slots], swz by q&7

    const int srow = qt * 64 + wid * 16 + l15;
    const short* qrow = q + ((size_t)(bb * SS + srow)) * DDIM + h * 64;
    bf16x8 qf[2];
    qf[0] = *(const bf16x8*)(qrow + g * 8);
    qf[1] = *(const bf16x8*)(qrow + 32 + g * 8);

    float m_run[4], l_run[4];
#pragma unroll
    for (int r = 0; r < 4; ++r) { m_run[r] = -1e30f; l_run[r] = 0.0f; }
    f32x4 oacc[4] = {};

    const int ntiles = (vlen + 63) >> 6;
    for (int t = 0; t < ntiles; ++t) {
        const int kb = t * 64;
        __syncthreads();   // prev tile's reads complete
        {
            // K: global_load_lds, dest linear, source pre-swizzled
#pragma unroll
            for (int j = 0; j < 2; ++j) {
                int c = tid + j * 256;
                int key = c >> 3, sp = c & 7;
                GL_LDS16(k + ((size_t)(bb * SS + kb + key)) * DDIM + h * 64 +
                             ((sp ^ (key & 7)) << 3),
                         (char*)&sK[0] + c * 16);
            }
            // V: register transpose scatter, swizzled
#pragma unroll
            for (int j = 0; j < 2; ++j) {
                int c = tid + j * 256;
                int key = c >> 3, d0 = (c & 7) << 3;
                bf16x8 vv = *(const bf16x8*)(v + ((size_t)(bb * SS + kb + key)) * DDIM + h * 64 + d0);
#pragma unroll
                for (int e = 0; e < 8; ++e) {
                    int ee = d0 + e;
                    sV[ee * 64 + (((key >> 3) ^ (ee & 7)) << 3) + (key & 7)] = vv[e];
                }
            }
        }
        __syncthreads();

        // QK^T: 16 q-rows x 64 keys per wave
        f32x4 sacc[4] = {};
#pragma unroll
        for (int kg = 0; kg < 4; ++kg) {
            int row = kg * 16 + l15;
#pragma unroll
            for (int kh = 0; kh < 2; ++kh) {
                int s = kh * 4 + g;
                bf16x8 kf = *(const bf16x8*)(&sK[row * 64 + ((s ^ (row & 7)) << 3)]);
                sacc[kg] = __builtin_amdgcn_mfma_f32_16x16x32_bf16(qf[kh], kf, sacc[kg], 0, 0, 0);
            }
        }

        // online softmax (rows g*4+r, cols = 4 groups x 16 lanes)
        float f[4];
#pragma unroll
        for (int r = 0; r < 4; ++r) {
            float s[4];
#pragma unroll
            for (int kg = 0; kg < 4; ++kg) {
                s[kg] = sacc[kg][r] * 0.125f;
                if (kb + kg * 16 + l15 >= vlen) s[kg] = -1e30f;
            }
            float tmax = fmaxf(fmaxf(s[0], s[1]), fmaxf(s[2], s[3]));
#pragma unroll
            for (int off = 1; off < 16; off <<= 1)
                tmax = fmaxf(tmax, __shfl_xor(tmax, off));
            float mn = fmaxf(m_run[r], tmax);
            f[r] = __expf(m_run[r] - mn);
            m_run[r] = mn;
            float p[4], rs = 0.0f;
#pragma unroll
            for (int kg = 0; kg < 4; ++kg) { p[kg] = __expf(s[kg] - mn); rs += p[kg]; }
#pragma unroll
            for (int off = 1; off < 16; off <<= 1)
                rs += __shfl_xor(rs, off);
            l_run[r] = l_run[r] * f[r] + rs;
            const int srw = g * 4 + r;
#pragma unroll
            for (int kg = 0; kg < 4; ++kg) {
                int col = kg * 16 + l15;
                sP[wid][srw * 64 + (((col >> 3) ^ (srw & 7)) << 3) + (col & 7)] = f2bf(p[kg]);
            }
        }
        // no barrier: sP wave-private; sK/sV protected by next-iter barrier

        // PV: contraction over 64 keys (2 k-halves)
        bf16x8 pf[2];
#pragma unroll
        for (int kh = 0; kh < 2; ++kh) {
            int s = kh * 4 + g;
            pf[kh] = *(const bf16x8*)(&sP[wid][l15 * 64 + ((s ^ (l15 & 7)) << 3)]);
        }
#pragma unroll
        for (int n = 0; n < 4; ++n) {
#pragma unroll
            for (int r = 0; r < 4; ++r) oacc[n][r] *= f[r];
            const int e = n * 16 + l15;
#pragma unroll
            for (int kh = 0; kh < 2; ++kh) {
                int s = kh * 4 + g;
                bf16x8 vf = *(const bf16x8*)(&sV[e * 64 + ((s ^ (e & 7)) << 3)]);
                oacc[n] = __builtin_amdgcn_mfma_f32_16x16x32_bf16(pf[kh], vf, oacc[n], 0, 0, 0);
            }
        }
    }

    // write head-interleaved: att[bb][s][e*H + h]
#pragma unroll
    for (int n = 0; n < 4; ++n)
#pragma unroll
        for (int r = 0; r < 4; ++r) {
            float o = oacc[n][r] / l_run[r];
            int sg = qt * 64 + wid * 16 + g * 4 + r;
            int e = n * 16 + l15;
            att[((size_t)(bb * SS + sg)) * DDIM + e * HH + h] = f2bf(o);
        }
}

extern "C" void kernel_launch(void* const* d_in, const int* in_sizes, int n_in,
                              void* d_out, int out_size, void* d_ws, size_t ws_size,
                              hipStream_t stream) {
    const float* queries = (const float*)d_in[0];
    const float* keys    = (const float*)d_in[1];
    const float* values  = (const float*)d_in[2];
    const int*   vlens   = (const int*)d_in[3];
    const float* Wq      = (const float*)d_in[4];
    const float* Wk      = (const float*)d_in[5];
    const float* Wv      = (const float*)d_in[6];
    const float* Wo      = (const float*)d_in[7];
    float* out = (float*)d_out;

    short* ws = (short*)d_ws;
    const size_t sz = (size_t)MROWS * DDIM;   // 4M elems
    short* q_ws   = ws;
    short* k_ws   = ws + sz;
    short* v_ws   = ws + 2 * sz;
    short* att_ws = ws + 3 * sz;
    short* wt3  = att_ws;                     // 6 MB of weights; dead until attn
    short* wt_o = q_ws;                       // dead after attn

    dim3 tgrid3(16, 16, 3);
    dim3 tgrid1(16, 16, 1);

    transposeW3<<<tgrid3, 256, 0, stream>>>(Wq, Wk, Wv, wt3);
    gemm<true, false><<<dim3(768), 256, 0, stream>>>(queries, keys, values, wt3,
                                                     q_ws, k_ws, v_ws);
    attn<<<dim3(1024), 256, 0, stream>>>(q_ws, k_ws, v_ws, vlens, att_ws);

    transposeW3<<<tgrid1, 256, 0, stream>>>(Wo, Wo, Wo, wt_o);
    gemm<false, true><<<dim3(256), 256, 0, stream>>>(att_ws, att_ws, att_ws, wt_o,
                                                     out, out, out);
}

// Round 7
// 135.054 us; speedup vs baseline: 2.1113x; 1.0945x over previous
//
#include <hip/hip_runtime.h>
#include <hip/hip_bf16.h>

#define BB 4
#define SS 1024
#define DDIM 1024
#define HH 16
#define MROWS (BB * SS)

typedef __attribute__((ext_vector_type(8))) short bf16x8;
typedef __attribute__((ext_vector_type(4))) float f32x4;

static __device__ __forceinline__ short f2bf(float x) {
    union { __hip_bfloat16 h; short s; } u;
    u.h = __float2bfloat16(x);
    return u.s;
}

#define GL_LDS16(gp, lp)                                                      \
    __builtin_amdgcn_global_load_lds(                                         \
        (const __attribute__((address_space(1))) void*)(gp),                  \
        (__attribute__((address_space(3))) void*)(lp), 16, 0, 0)

// ---------------------------------------------------------------------------
// Weight transpose+convert: W [K,N] f32 -> Wt [N,K] bf16. 64x64 tiles.
__global__ __launch_bounds__(256) void transposeW3(const float* __restrict__ W0,
                                                   const float* __restrict__ W1,
                                                   const float* __restrict__ W2,
                                                   short* __restrict__ Wt) {
    const int z = blockIdx.z;
    const float* W = (z == 0) ? W0 : (z == 1) ? W1 : W2;
    short* dst = Wt + (size_t)z * DDIM * DDIM;
    __shared__ short sT[64][72];
    const int t = threadIdx.x;
    const int k0 = blockIdx.y * 64, n0 = blockIdx.x * 64;
    {
        int r = t >> 2, cq = (t & 3) << 4;
        const float* p = W + (size_t)(k0 + r) * DDIM + n0 + cq;
        float4 a = ((const float4*)p)[0], b = ((const float4*)p)[1];
        float4 c = ((const float4*)p)[2], d = ((const float4*)p)[3];
        short* dp = &sT[r][cq];
        dp[0]  = f2bf(a.x); dp[1]  = f2bf(a.y); dp[2]  = f2bf(a.z); dp[3]  = f2bf(a.w);
        dp[4]  = f2bf(b.x); dp[5]  = f2bf(b.y); dp[6]  = f2bf(b.z); dp[7]  = f2bf(b.w);
        dp[8]  = f2bf(c.x); dp[9]  = f2bf(c.y); dp[10] = f2bf(c.z); dp[11] = f2bf(c.w);
        dp[12] = f2bf(d.x); dp[13] = f2bf(d.y); dp[14] = f2bf(d.z); dp[15] = f2bf(d.w);
    }
    __syncthreads();
    {
        int n = t >> 2, kq = (t & 3) << 4;
        bf16x8 o0, o1;
#pragma unroll
        for (int j = 0; j < 8; ++j) o0[j] = sT[kq + j][n];
#pragma unroll
        for (int j = 0; j < 8; ++j) o1[j] = sT[kq + 8 + j][n];
        short* q = dst + (size_t)(n0 + n) * DDIM + k0 + kq;
        *(bf16x8*)q = o0;
        *(bf16x8*)(q + 8) = o1;
    }
}

// ---------------------------------------------------------------------------
// C[z][M,N] = A[z][M,K] @ Bt[z][N,K]^T, up to 3 fused problems.
// BM=128, BN template (128 or 64), BK=32 double-buffered (LDS 32/24 KB ->
// 3-5 blocks/CU), XOR swizzle slot' = s ^ (row&3) on 16B slots, XCD-chunked.
// 256 thr = 4 waves (2x2), wave tile 64 x BN/2.
template<bool A_F32, bool C_F32, int BN>
__global__ __launch_bounds__(256) void gemm(const void* __restrict__ A0v,
                                            const void* __restrict__ A1v,
                                            const void* __restrict__ A2v,
                                            const short* __restrict__ BtBase,
                                            void* __restrict__ C0v,
                                            void* __restrict__ C1v,
                                            void* __restrict__ C2v) {
    constexpr int NJ  = BN / 32;        // acc cols per wave
    constexpr int NBX = DDIM / BN;      // col panels
    constexpr int NPB = 32 * NBX;       // blocks per problem
    constexpr int BCH = BN / 64;        // B chunks per thread

    __shared__ short sA[2][128 * 32];   // 8 KB per buf
    __shared__ short sB[2][BN * 32];    // 8 or 4 KB per buf

    const int tid = threadIdx.x;
    const int lane = tid & 63, wid = tid >> 6;
    const int wr = wid >> 1, wc = wid & 1;
    const int g = lane >> 4, l15 = lane & 15;

    const int blk = blockIdx.x;
    const int z = blk / NPB;
    const int inner = blk % NPB;
    const int xcd = inner & 7, ii = inner >> 3;   // ii in [0, 4*NBX)
    const int by = xcd * 4 + ii / NBX;            // 32 row panels, 4 per XCD
    const int bx = ii % NBX;

    const void* Av = (z == 0) ? A0v : (z == 1) ? A1v : A2v;
    const short* Bt = BtBase + (size_t)z * DDIM * DDIM;
    void* Cv = (z == 0) ? C0v : (z == 1) ? C1v : C2v;
    const float* Af = (const float*)Av;
    const short* Ab = (const short*)Av;
    const int K = DDIM;

    f32x4 acc[4][NJ] = {};
    const int nkt = K >> 5;   // 32 K-steps

    // ---- prologue: stage tile 0 into buf 0 ----
    if constexpr (A_F32) {
#pragma unroll
        for (int j = 0; j < 2; ++j) {
            int c = tid + j * 256;
            int row = c >> 2, s = c & 3;
            const float* p = Af + (size_t)(by * 128 + row) * K + s * 8;
            float4 x0 = ((const float4*)p)[0];
            float4 x1 = ((const float4*)p)[1];
            bf16x8 vv;
            vv[0] = f2bf(x0.x); vv[1] = f2bf(x0.y); vv[2] = f2bf(x0.z); vv[3] = f2bf(x0.w);
            vv[4] = f2bf(x1.x); vv[5] = f2bf(x1.y); vv[6] = f2bf(x1.z); vv[7] = f2bf(x1.w);
            *(bf16x8*)(&sA[0][row * 32 + ((s ^ (row & 3)) << 3)]) = vv;
        }
    } else {
#pragma unroll
        for (int j = 0; j < 2; ++j) {
            int c = tid + j * 256;
            int row = c >> 2, sp = c & 3;
            GL_LDS16(Ab + (size_t)(by * 128 + row) * K + ((sp ^ (row & 3)) << 3),
                     (char*)&sA[0][0] + c * 16);
        }
    }
#pragma unroll
    for (int j = 0; j < BCH; ++j) {
        int c = tid + j * 256;
        int row = c >> 2, sp = c & 3;
        GL_LDS16(Bt + (size_t)(bx * BN + row) * K + ((sp ^ (row & 3)) << 3),
                 (char*)&sB[0][0] + c * 16);
    }

    for (int t = 0; t < nkt; ++t) {
        const int cur = t & 1, nxt = cur ^ 1;
        __syncthreads();   // buf[cur] ready; prev reads of buf[nxt] done

        const bool pre = (t + 1 < nkt);
        float4 ra[2][2];
        if (pre) {
            const int kt = (t + 1) << 5;
            if constexpr (A_F32) {
#pragma unroll
                for (int j = 0; j < 2; ++j) {
                    int c = tid + j * 256;
                    int row = c >> 2, s = c & 3;
                    const float* p = Af + (size_t)(by * 128 + row) * K + kt + s * 8;
                    ra[j][0] = ((const float4*)p)[0];
                    ra[j][1] = ((const float4*)p)[1];
                }
            } else {
#pragma unroll
                for (int j = 0; j < 2; ++j) {
                    int c = tid + j * 256;
                    int row = c >> 2, sp = c & 3;
                    GL_LDS16(Ab + (size_t)(by * 128 + row) * K + kt + ((sp ^ (row & 3)) << 3),
                             (char*)&sA[nxt][0] + c * 16);
                }
            }
#pragma unroll
            for (int j = 0; j < BCH; ++j) {
                int c = tid + j * 256;
                int row = c >> 2, sp = c & 3;
                GL_LDS16(Bt + (size_t)(bx * BN + row) * K + kt + ((sp ^ (row & 3)) << 3),
                         (char*)&sB[nxt][0] + c * 16);
            }
        }

        bf16x8 af[4], bfr[NJ];
#pragma unroll
        for (int i = 0; i < 4; ++i) {
            int row = wr * 64 + i * 16 + l15;
            af[i] = *(const bf16x8*)(&sA[cur][row * 32 + ((g ^ (row & 3)) << 3)]);
        }
#pragma unroll
        for (int j = 0; j < NJ; ++j) {
            int row = wc * (BN / 2) + j * 16 + l15;
            bfr[j] = *(const bf16x8*)(&sB[cur][row * 32 + ((g ^ (row & 3)) << 3)]);
        }
#pragma unroll
        for (int i = 0; i < 4; ++i)
#pragma unroll
            for (int j = 0; j < NJ; ++j)
                acc[i][j] = __builtin_amdgcn_mfma_f32_16x16x32_bf16(af[i], bfr[j], acc[i][j], 0, 0, 0);

        if (pre) {
            if constexpr (A_F32) {
#pragma unroll
                for (int j = 0; j < 2; ++j) {
                    int c = tid + j * 256;
                    int row = c >> 2, s = c & 3;
                    bf16x8 vv;
                    vv[0] = f2bf(ra[j][0].x); vv[1] = f2bf(ra[j][0].y);
                    vv[2] = f2bf(ra[j][0].z); vv[3] = f2bf(ra[j][0].w);
                    vv[4] = f2bf(ra[j][1].x); vv[5] = f2bf(ra[j][1].y);
                    vv[6] = f2bf(ra[j][1].z); vv[7] = f2bf(ra[j][1].w);
                    *(bf16x8*)(&sA[nxt][row * 32 + ((s ^ (row & 3)) << 3)]) = vv;
                }
            }
        }
    }

#pragma unroll
    for (int i = 0; i < 4; ++i)
#pragma unroll
        for (int j = 0; j < NJ; ++j)
#pragma unroll
            for (int r = 0; r < 4; ++r) {
                int row = by * 128 + wr * 64 + i * 16 + g * 4 + r;
                int col = bx * BN + wc * (BN / 2) + j * 16 + l15;
                if constexpr (C_F32)
                    ((float*)Cv)[(size_t)row * DDIM + col] = acc[i][j][r];
                else
                    ((short*)Cv)[(size_t)row * DDIM + col] = f2bf(acc[i][j][r]);
            }
}

// ---------------------------------------------------------------------------
// Flash attention per (b, h, 64-q-rows). 4 waves x 16 q-rows, KV tiles of 64.
// Batch-interleaved block order (load balance); swizzled sK/sV/sP; K staged
// via global_load_lds (pre-swizzled source); 2 barriers per 64-key tile.
__global__ __launch_bounds__(256) void attn(const short* __restrict__ q,
                                            const short* __restrict__ k,
                                            const short* __restrict__ v,
                                            const int* __restrict__ vlens,
                                            short* __restrict__ att) {
    const int blk = blockIdx.x;            // 1024
    const int qt = blk >> 6;               // 0..15
    const int hb = blk & 63;
    const int bb = hb & 3;                 // batch varies fastest
    const int h  = hb >> 2;

    const int tid = threadIdx.x;
    const int lane = tid & 63, wid = tid >> 6;
    const int g = lane >> 4, l15 = lane & 15;
    const int vlen = vlens[bb];

    __shared__ short sK[64 * 64];          // [key][d-slots], swz by key&7
    __shared__ short sV[64 * 64];          // [e][key-slots], swz by e&7
    __shared__ short sP[4][16 * 64];       // per-wave [q][key-slots], swz by q&7

    const int srow = qt * 64 + wid * 16 + l15;
    const short* qrow = q + ((size_t)(bb * SS + srow)) * DDIM + h * 64;
    bf16x8 qf[2];
    qf[0] = *(const bf16x8*)(qrow + g * 8);
    qf[1] = *(const bf16x8*)(qrow + 32 + g * 8);

    float m_run[4], l_run[4];
#pragma unroll
    for (int r = 0; r < 4; ++r) { m_run[r] = -1e30f; l_run[r] = 0.0f; }
    f32x4 oacc[4] = {};

    const int ntiles = (vlen + 63) >> 6;
    for (int t = 0; t < ntiles; ++t) {
        const int kb = t * 64;
        __syncthreads();   // prev tile's reads complete
        {
#pragma unroll
            for (int j = 0; j < 2; ++j) {
                int c = tid + j * 256;
                int key = c >> 3, sp = c & 7;
                GL_LDS16(k + ((size_t)(bb * SS + kb + key)) * DDIM + h * 64 +
                             ((sp ^ (key & 7)) << 3),
                         (char*)&sK[0] + c * 16);
            }
#pragma unroll
            for (int j = 0; j < 2; ++j) {
                int c = tid + j * 256;
                int key = c >> 3, d0 = (c & 7) << 3;
                bf16x8 vv = *(const bf16x8*)(v + ((size_t)(bb * SS + kb + key)) * DDIM + h * 64 + d0);
#pragma unroll
                for (int e = 0; e < 8; ++e) {
                    int ee = d0 + e;
                    sV[ee * 64 + (((key >> 3) ^ (ee & 7)) << 3) + (key & 7)] = vv[e];
                }
            }
        }
        __syncthreads();

        // QK^T: 16 q-rows x 64 keys per wave
        f32x4 sacc[4] = {};
#pragma unroll
        for (int kg = 0; kg < 4; ++kg) {
            int row = kg * 16 + l15;
#pragma unroll
            for (int kh = 0; kh < 2; ++kh) {
                int s = kh * 4 + g;
                bf16x8 kf = *(const bf16x8*)(&sK[row * 64 + ((s ^ (row & 7)) << 3)]);
                sacc[kg] = __builtin_amdgcn_mfma_f32_16x16x32_bf16(qf[kh], kf, sacc[kg], 0, 0, 0);
            }
        }

        // online softmax
        float f[4];
#pragma unroll
        for (int r = 0; r < 4; ++r) {
            float s[4];
#pragma unroll
            for (int kg = 0; kg < 4; ++kg) {
                s[kg] = sacc[kg][r] * 0.125f;
                if (kb + kg * 16 + l15 >= vlen) s[kg] = -1e30f;
            }
            float tmax = fmaxf(fmaxf(s[0], s[1]), fmaxf(s[2], s[3]));
#pragma unroll
            for (int off = 1; off < 16; off <<= 1)
                tmax = fmaxf(tmax, __shfl_xor(tmax, off));
            float mn = fmaxf(m_run[r], tmax);
            f[r] = __expf(m_run[r] - mn);
            m_run[r] = mn;
            float p[4], rs = 0.0f;
#pragma unroll
            for (int kg = 0; kg < 4; ++kg) { p[kg] = __expf(s[kg] - mn); rs += p[kg]; }
#pragma unroll
            for (int off = 1; off < 16; off <<= 1)
                rs += __shfl_xor(rs, off);
            l_run[r] = l_run[r] * f[r] + rs;
            const int srw = g * 4 + r;
#pragma unroll
            for (int kg = 0; kg < 4; ++kg) {
                int col = kg * 16 + l15;
                sP[wid][srw * 64 + (((col >> 3) ^ (srw & 7)) << 3) + (col & 7)] = f2bf(p[kg]);
            }
        }
        // no barrier: sP wave-private; sK/sV protected by next-iter barrier

        // PV
        bf16x8 pf[2];
#pragma unroll
        for (int kh = 0; kh < 2; ++kh) {
            int s = kh * 4 + g;
            pf[kh] = *(const bf16x8*)(&sP[wid][l15 * 64 + ((s ^ (l15 & 7)) << 3)]);
        }
#pragma unroll
        for (int n = 0; n < 4; ++n) {
#pragma unroll
            for (int r = 0; r < 4; ++r) oacc[n][r] *= f[r];
            const int e = n * 16 + l15;
#pragma unroll
            for (int kh = 0; kh < 2; ++kh) {
                int s = kh * 4 + g;
                bf16x8 vf = *(const bf16x8*)(&sV[e * 64 + ((s ^ (e & 7)) << 3)]);
                oacc[n] = __builtin_amdgcn_mfma_f32_16x16x32_bf16(pf[kh], vf, oacc[n], 0, 0, 0);
            }
        }
    }

    // write head-interleaved: att[bb][s][e*H + h]
#pragma unroll
    for (int n = 0; n < 4; ++n)
#pragma unroll
        for (int r = 0; r < 4; ++r) {
            float o = oacc[n][r] / l_run[r];
            int sg = qt * 64 + wid * 16 + g * 4 + r;
            int e = n * 16 + l15;
            att[((size_t)(bb * SS + sg)) * DDIM + e * HH + h] = f2bf(o);
        }
}

extern "C" void kernel_launch(void* const* d_in, const int* in_sizes, int n_in,
                              void* d_out, int out_size, void* d_ws, size_t ws_size,
                              hipStream_t stream) {
    const float* queries = (const float*)d_in[0];
    const float* keys    = (const float*)d_in[1];
    const float* values  = (const float*)d_in[2];
    const int*   vlens   = (const int*)d_in[3];
    const float* Wq      = (const float*)d_in[4];
    const float* Wk      = (const float*)d_in[5];
    const float* Wv      = (const float*)d_in[6];
    const float* Wo      = (const float*)d_in[7];
    float* out = (float*)d_out;

    short* ws = (short*)d_ws;
    const size_t sz = (size_t)MROWS * DDIM;   // 4M elems
    short* q_ws   = ws;
    short* k_ws   = ws + sz;
    short* v_ws   = ws + 2 * sz;
    short* att_ws = ws + 3 * sz;
    short* wt3  = att_ws;                     // weights; dead until attn writes
    short* wt_o = q_ws;                       // dead after attn

    dim3 tgrid3(16, 16, 3);
    dim3 tgrid1(16, 16, 1);

    transposeW3<<<tgrid3, 256, 0, stream>>>(Wq, Wk, Wv, wt3);
    gemm<true, false, 128><<<dim3(768), 256, 0, stream>>>(queries, keys, values, wt3,
                                                          q_ws, k_ws, v_ws);
    attn<<<dim3(1024), 256, 0, stream>>>(q_ws, k_ws, v_ws, vlens, att_ws);

    transposeW3<<<tgrid1, 256, 0, stream>>>(Wo, Wo, Wo, wt_o);
    gemm<false, true, 64><<<dim3(512), 256, 0, stream>>>(att_ws, att_ws, att_ws, wt_o,
                                                         out, out, out);
}